// Round 1
// baseline (695.157 us; speedup 1.0000x reference)
//
#include <hip/hip_runtime.h>

// Problem constants (from reference):
//   embeddings [B=2][F=32][D*H*W = 2359296] f32
//   labels     [B][N] i32 in [0,15); cls = min(label, 11)
//   prototypes [C=12][F=32] f32 ; out same shape
#define B_      2
#define F_      32
#define C_      12
#define NVOX    2359296L            // 64*192*192
#define THREADS 256
#define VPT     32                  // voxels per thread
#define CHUNK   (THREADS * VPT)     // 8192
#define NBLK    288                 // NVOX / CHUNK (exact)
#define FT      4                   // feature tile (masks amortized over FT)

__device__ __forceinline__ float wave_reduce(float v) {
#pragma unroll
    for (int off = 32; off > 0; off >>= 1)
        v += __shfl_down(v, off, 64);
    return v;
}

__device__ __forceinline__ float f4_get(const float4& v, int j) {
    // j is compile-time constant at every call site (folds to a register pick)
    switch (j) {
        case 0:  return v.x;
        case 1:  return v.y;
        case 2:  return v.z;
        default: return v.w;
    }
}

__global__ __launch_bounds__(THREADS)
void accum_kernel(const float* __restrict__ emb,
                  const int*   __restrict__ labels,
                  float*       __restrict__ g_sums,   // [B][C][F]
                  float*       __restrict__ g_cnts) { // [B][C]
    const int  b   = blockIdx.y;
    const int  tid = threadIdx.x;
    const long n0  = (long)blockIdx.x * CHUNK;

    __shared__ float lds_sums[C_ * F_];
    __shared__ float lds_cnts[C_];
    if (tid < C_ * F_) lds_sums[tid] = 0.f;
    if (tid < C_)      lds_cnts[tid] = 0.f;
    __syncthreads();

    // ---- load 32 labels/thread once, clamp to 11, pack 4 bits each ----
    // voxel for (i,j): n0 + i*1024 + tid*4 + j   (i=0..7, j=0..3)
    // element e = i*4 + j ; nibble index e&7 within word e>>3
    unsigned pack[4];
    {
        const int4* lab4 = (const int4*)(labels + (long)b * NVOX + n0);
#pragma unroll
        for (int i = 0; i < 8; ++i) {
            int4 L = lab4[i * THREADS + tid];
            unsigned c0 = (unsigned)min(L.x, 11);
            unsigned c1 = (unsigned)min(L.y, 11);
            unsigned c2 = (unsigned)min(L.z, 11);
            unsigned c3 = (unsigned)min(L.w, 11);
            unsigned nib = c0 | (c1 << 4) | (c2 << 8) | (c3 << 12);
            if (i & 1) pack[i >> 1] |= nib << 16;
            else       pack[i >> 1]  = nib;
        }
    }

    // ---- per-class counts (once per voxel) ----
    {
        float cacc[C_];
#pragma unroll
        for (int c = 0; c < C_; ++c) cacc[c] = 0.f;
#pragma unroll
        for (int e = 0; e < VPT; ++e) {
            unsigned cl = (pack[e >> 3] >> ((e & 7) * 4)) & 0xFu;
#pragma unroll
            for (int c = 0; c < C_; ++c)
                cacc[c] += (cl == (unsigned)c) ? 1.f : 0.f;
        }
#pragma unroll
        for (int c = 0; c < C_; ++c) {
            float v = wave_reduce(cacc[c]);
            if ((tid & 63) == 0) atomicAdd(&lds_cnts[c], v);
        }
    }

    // ---- main accumulation: F tiled by FT, masks amortized over the tile ----
    const float4* emb4 = (const float4*)emb;
#pragma unroll 1
    for (int ft = 0; ft < F_; ft += FT) {
        float acc[C_][FT];
#pragma unroll
        for (int c = 0; c < C_; ++c)
#pragma unroll
            for (int fo = 0; fo < FT; ++fo) acc[c][fo] = 0.f;

#pragma unroll
        for (int i = 0; i < 8; ++i) {
            float4 v[FT];
#pragma unroll
            for (int fo = 0; fo < FT; ++fo) {
                const long base4 = ((long)(b * F_ + ft + fo) * NVOX + n0) >> 2;
                v[fo] = emb4[base4 + i * THREADS + tid];
            }
#pragma unroll
            for (int j = 0; j < 4; ++j) {
                const int e = i * 4 + j;
                const unsigned cl = (pack[e >> 3] >> ((e & 7) * 4)) & 0xFu;
                float m[C_];
#pragma unroll
                for (int c = 0; c < C_; ++c)
                    m[c] = (cl == (unsigned)c) ? 1.f : 0.f;
#pragma unroll
                for (int c = 0; c < C_; ++c)
#pragma unroll
                    for (int fo = 0; fo < FT; ++fo)
                        acc[c][fo] = fmaf(f4_get(v[fo], j), m[c], acc[c][fo]);
            }
        }

        // wave-reduce each (c, fo), one LDS atomic per wave
#pragma unroll
        for (int c = 0; c < C_; ++c)
#pragma unroll
            for (int fo = 0; fo < FT; ++fo) {
                float v = wave_reduce(acc[c][fo]);
                if ((tid & 63) == 0) atomicAdd(&lds_sums[c * F_ + ft + fo], v);
            }
    }

    __syncthreads();
    if (tid < C_ * F_) atomicAdd(&g_sums[b * C_ * F_ + tid], lds_sums[tid]);
    if (tid < C_)      atomicAdd(&g_cnts[b * C_ + tid],      lds_cnts[tid]);
}

__global__ void finalize_kernel(const float* __restrict__ g_sums,
                                const float* __restrict__ g_cnts,
                                const float* __restrict__ proto,
                                float*       __restrict__ out) {
    const int idx = threadIdx.x;           // 0..383 = c*F + f
    if (idx >= C_ * F_) return;
    const int c = idx / F_;
    float p = proto[idx];
#pragma unroll
    for (int b = 0; b < B_; ++b) {
        const float cnt = g_cnts[b * C_ + c];
        const float s   = g_sums[b * C_ * F_ + idx];
        if (cnt > 0.f) p = 0.9f * p + 0.1f * (s / cnt);
    }
    out[idx] = p;
}

extern "C" void kernel_launch(void* const* d_in, const int* in_sizes, int n_in,
                              void* d_out, int out_size, void* d_ws, size_t ws_size,
                              hipStream_t stream) {
    const float* emb    = (const float*)d_in[0];
    const int*   labels = (const int*)d_in[1];
    const float* proto  = (const float*)d_in[2];
    float*       out    = (float*)d_out;

    float* g_sums = (float*)d_ws;              // B*C*F = 768 floats
    float* g_cnts = g_sums + B_ * C_ * F_;     // B*C   = 24 floats

    hipMemsetAsync(d_ws, 0, (size_t)(B_ * C_ * F_ + B_ * C_) * sizeof(float), stream);

    dim3 grid(NBLK, B_);
    accum_kernel<<<grid, THREADS, 0, stream>>>(emb, labels, g_sums, g_cnts);
    finalize_kernel<<<1, C_ * F_, 0, stream>>>(g_sums, g_cnts, proto, out);
}

// Round 2
// 162.341 us; speedup vs baseline: 4.2821x; 4.2821x over previous
//
#include <hip/hip_runtime.h>

// embeddings [B=2][F=32][N=2359296] f32, labels [B][N] i32, prototypes [12][32] f32
// sums[c][f] = sum_n onehot[c][n] * emb[f][n]  ==  mfma(A=onehot, B=emb)
// mfma_f32_16x16x32_bf16 operand layout: lane l holds outdim = l&15,
// k = 8*(l>>4)+j (j=0..7);  C/D: col = l&15, row = (l>>4)*4 + reg.
#define B_        2
#define F_        32
#define C_        12
#define NVOX      2359296L
#define THREADS   256
#define WAVE_SPAN 2048                 // voxels per wave
#define BLOCK_SPAN (WAVE_SPAN * 4)     // 8192
#define NBLK      288                  // NVOX / BLOCK_SPAN exactly
#define KSTEPS    (WAVE_SPAN / 32)     // 64 mfma K-steps per wave

typedef __attribute__((ext_vector_type(8))) short short8;   // 8 bf16 (4 VGPRs)
typedef __attribute__((ext_vector_type(4))) float f32x4;

union ABu { short8 s; __bf16 h[8]; unsigned u[4]; };

__global__ __launch_bounds__(THREADS)
void accum_mfma(const float* __restrict__ emb,
                const int*   __restrict__ labels,
                float*       __restrict__ g_sums,   // [B][C][F]
                float*       __restrict__ g_cnts) { // [B][C]
    const int b    = blockIdx.y;
    const int tid  = threadIdx.x;
    const int wv   = tid >> 6;
    const int lane = tid & 63;
    const int fcol = lane & 15;        // feature col (and one-hot row) index
    const int kgrp = lane >> 4;        // 0..3, k-base = kgrp*8

    const long n0 = (long)blockIdx.x * BLOCK_SPAN + (long)wv * WAVE_SPAN + (kgrp << 3);

    const int*   lab = labels + (long)b * NVOX + n0;
    const float* e0  = emb + (long)(b * F_ + fcol) * NVOX + n0;        // features 0..15
    const float* e1  = e0 + 16L * NVOX;                                // features 16..31

    ABu ones;
#pragma unroll
    for (int p = 0; p < 4; ++p) ones.u[p] = 0x3F803F80u;   // bf16 1.0 pairs

    f32x4 acc0 = {0.f, 0.f, 0.f, 0.f};   // sums, features 0..15
    f32x4 acc1 = {0.f, 0.f, 0.f, 0.f};   // sums, features 16..31
    f32x4 acc2 = {0.f, 0.f, 0.f, 0.f};   // counts (all cols identical)

#pragma unroll 2
    for (int s = 0; s < KSTEPS; ++s) {
        // 8 labels for this lane's k-slots (16-lane groups share -> coalesced 128B/wave)
        int4 L0 = *(const int4*)(lab);
        int4 L1 = *(const int4*)(lab + 4);
        // 8 consecutive voxels of this lane's two features
        float4 v00 = *(const float4*)(e0);
        float4 v01 = *(const float4*)(e0 + 4);
        float4 v10 = *(const float4*)(e1);
        float4 v11 = *(const float4*)(e1 + 4);

        // A fragment: onehot[row=fcol][k] as bf16 {0,1}
        ABu a;
        {
            const int r = fcol;
            unsigned m0 = (min(L0.x, 11) == r) ? 0x3F80u : 0u;
            unsigned m1 = (min(L0.y, 11) == r) ? 0x3F80u : 0u;
            unsigned m2 = (min(L0.z, 11) == r) ? 0x3F80u : 0u;
            unsigned m3 = (min(L0.w, 11) == r) ? 0x3F80u : 0u;
            unsigned m4 = (min(L1.x, 11) == r) ? 0x3F80u : 0u;
            unsigned m5 = (min(L1.y, 11) == r) ? 0x3F80u : 0u;
            unsigned m6 = (min(L1.z, 11) == r) ? 0x3F80u : 0u;
            unsigned m7 = (min(L1.w, 11) == r) ? 0x3F80u : 0u;
            a.u[0] = m0 | (m1 << 16);
            a.u[1] = m2 | (m3 << 16);
            a.u[2] = m4 | (m5 << 16);
            a.u[3] = m6 | (m7 << 16);
        }

        // B fragments: emb cast to bf16 (RNE via v_cvt_pk_bf16_f32)
        ABu b0, b1;
        b0.h[0] = (__bf16)v00.x; b0.h[1] = (__bf16)v00.y;
        b0.h[2] = (__bf16)v00.z; b0.h[3] = (__bf16)v00.w;
        b0.h[4] = (__bf16)v01.x; b0.h[5] = (__bf16)v01.y;
        b0.h[6] = (__bf16)v01.z; b0.h[7] = (__bf16)v01.w;
        b1.h[0] = (__bf16)v10.x; b1.h[1] = (__bf16)v10.y;
        b1.h[2] = (__bf16)v10.z; b1.h[3] = (__bf16)v10.w;
        b1.h[4] = (__bf16)v11.x; b1.h[5] = (__bf16)v11.y;
        b1.h[6] = (__bf16)v11.z; b1.h[7] = (__bf16)v11.w;

        acc0 = __builtin_amdgcn_mfma_f32_16x16x32_bf16(a.s, b0.s,   acc0, 0, 0, 0);
        acc1 = __builtin_amdgcn_mfma_f32_16x16x32_bf16(a.s, b1.s,   acc1, 0, 0, 0);
        acc2 = __builtin_amdgcn_mfma_f32_16x16x32_bf16(a.s, ones.s, acc2, 0, 0, 0);

        lab += 32; e0 += 32; e1 += 32;
    }

    // ---- block reduction: LDS atomics (conflict-free within a wave) ----
    __shared__ float lsum[16 * 32];
    __shared__ float lcnt[16];
    for (int i = tid; i < 16 * 32; i += THREADS) lsum[i] = 0.f;
    if (tid < 16) lcnt[tid] = 0.f;
    __syncthreads();

#pragma unroll
    for (int r = 0; r < 4; ++r) {
        const int c = (kgrp << 2) + r;          // D row = class
        atomicAdd(&lsum[c * 32 + fcol],      acc0[r]);
        atomicAdd(&lsum[c * 32 + 16 + fcol], acc1[r]);
    }
    if (fcol == 0) {
#pragma unroll
        for (int r = 0; r < 4; ++r) atomicAdd(&lcnt[(kgrp << 2) + r], acc2[r]);
    }
    __syncthreads();

    if (tid < C_ * F_) atomicAdd(&g_sums[b * (C_ * F_) + tid], lsum[tid]); // c=tid/32<12
    if (tid < C_)      atomicAdd(&g_cnts[b * C_ + tid],        lcnt[tid]);
}

__global__ void finalize_kernel(const float* __restrict__ g_sums,
                                const float* __restrict__ g_cnts,
                                const float* __restrict__ proto,
                                float*       __restrict__ out) {
    const int idx = threadIdx.x;               // 0..383 = c*F + f
    if (idx >= C_ * F_) return;
    const int c = idx / F_;
    float p = proto[idx];
#pragma unroll
    for (int b = 0; b < B_; ++b) {
        const float cnt = g_cnts[b * C_ + c];
        const float s   = g_sums[b * C_ * F_ + idx];
        if (cnt > 0.f) p = 0.9f * p + 0.1f * (s / cnt);
    }
    out[idx] = p;
}

extern "C" void kernel_launch(void* const* d_in, const int* in_sizes, int n_in,
                              void* d_out, int out_size, void* d_ws, size_t ws_size,
                              hipStream_t stream) {
    const float* emb    = (const float*)d_in[0];
    const int*   labels = (const int*)d_in[1];
    const float* proto  = (const float*)d_in[2];
    float*       out    = (float*)d_out;

    float* g_sums = (float*)d_ws;              // 768 floats
    float* g_cnts = g_sums + B_ * C_ * F_;     // 24 floats

    hipMemsetAsync(d_ws, 0, (size_t)(B_ * C_ * F_ + B_ * C_) * sizeof(float), stream);

    dim3 grid(NBLK, B_);
    accum_mfma<<<grid, THREADS, 0, stream>>>(emb, labels, g_sums, g_cnts);
    finalize_kernel<<<1, C_ * F_, 0, stream>>>(g_sums, g_cnts, proto, out);
}

// Round 3
// 139.934 us; speedup vs baseline: 4.9677x; 1.1601x over previous
//
#include <hip/hip_runtime.h>

// embeddings [B=2][F=32][N=2359296] f32, labels [B][N] i32, prototypes [12][32] f32
// sums[c][f] = sum_n onehot[c][n] * emb[f][n]  ==  mfma(A=onehot, B=emb)
// mfma_f32_16x16x32_bf16 operand layout: lane l holds outdim = l&15,
// k = 8*(l>>4)+j (j=0..7);  C/D: col = l&15, row = (l>>4)*4 + reg.
#define B_        2
#define F_        32
#define C_        12
#define NVOX      2359296L
#define THREADS   256
#define WAVE_SPAN 512                  // voxels per wave
#define BLOCK_SPAN (WAVE_SPAN * 4)     // 2048
#define NBLK      1152                 // NVOX / BLOCK_SPAN (exact); 2304 total = 9/CU
#define KSTEPS    (WAVE_SPAN / 32)     // 16 mfma K-steps per wave

typedef __attribute__((ext_vector_type(8))) short short8;   // 8 bf16 (4 VGPRs)
typedef __attribute__((ext_vector_type(4))) float f32x4;

union ABu { short8 s; __bf16 h[8]; unsigned u[4]; };

__global__ __launch_bounds__(THREADS)
void accum_mfma(const float* __restrict__ emb,
                const int*   __restrict__ labels,
                float*       __restrict__ g_sums,   // [B][C][F]
                float*       __restrict__ g_cnts) { // [B][C]
    const int b    = blockIdx.y;
    const int tid  = threadIdx.x;
    const int wv   = tid >> 6;
    const int lane = tid & 63;
    const int fcol = lane & 15;        // feature col (and one-hot class row) index
    const int kgrp = lane >> 4;        // 0..3, k-base = kgrp*8

    const long n0 = (long)blockIdx.x * BLOCK_SPAN + (long)wv * WAVE_SPAN + (kgrp << 3);

    const int*   lab = labels + (long)b * NVOX + n0;
    const float* e0  = emb + (long)(b * F_ + fcol) * NVOX + n0;        // features 0..15
    const float* e1  = e0 + 16L * NVOX;                                // features 16..31

    ABu ones;
#pragma unroll
    for (int p = 0; p < 4; ++p) ones.u[p] = 0x3F803F80u;   // bf16 1.0 pairs

    f32x4 acc0 = {0.f, 0.f, 0.f, 0.f};   // sums, features 0..15
    f32x4 acc1 = {0.f, 0.f, 0.f, 0.f};   // sums, features 16..31
    f32x4 acc2 = {0.f, 0.f, 0.f, 0.f};   // counts (all cols identical)

#pragma unroll 2
    for (int s = 0; s < KSTEPS; ++s) {
        // 8 labels for this lane's k-slots (16-lane groups share -> one transaction)
        int4 L0 = *(const int4*)(lab);
        int4 L1 = *(const int4*)(lab + 4);
        // 8 consecutive voxels of this lane's two features
        float4 v00 = *(const float4*)(e0);
        float4 v01 = *(const float4*)(e0 + 4);
        float4 v10 = *(const float4*)(e1);
        float4 v11 = *(const float4*)(e1 + 4);

        // A fragment: onehot[row=fcol][k] as bf16 {0,1}
        ABu a;
        {
            const int r = fcol;
            unsigned m0 = (min(L0.x, 11) == r) ? 0x3F80u : 0u;
            unsigned m1 = (min(L0.y, 11) == r) ? 0x3F80u : 0u;
            unsigned m2 = (min(L0.z, 11) == r) ? 0x3F80u : 0u;
            unsigned m3 = (min(L0.w, 11) == r) ? 0x3F80u : 0u;
            unsigned m4 = (min(L1.x, 11) == r) ? 0x3F80u : 0u;
            unsigned m5 = (min(L1.y, 11) == r) ? 0x3F80u : 0u;
            unsigned m6 = (min(L1.z, 11) == r) ? 0x3F80u : 0u;
            unsigned m7 = (min(L1.w, 11) == r) ? 0x3F80u : 0u;
            a.u[0] = m0 | (m1 << 16);
            a.u[1] = m2 | (m3 << 16);
            a.u[2] = m4 | (m5 << 16);
            a.u[3] = m6 | (m7 << 16);
        }

        // B fragments: emb cast to bf16 (RNE via v_cvt_pk_bf16_f32)
        ABu b0, b1;
        b0.h[0] = (__bf16)v00.x; b0.h[1] = (__bf16)v00.y;
        b0.h[2] = (__bf16)v00.z; b0.h[3] = (__bf16)v00.w;
        b0.h[4] = (__bf16)v01.x; b0.h[5] = (__bf16)v01.y;
        b0.h[6] = (__bf16)v01.z; b0.h[7] = (__bf16)v01.w;
        b1.h[0] = (__bf16)v10.x; b1.h[1] = (__bf16)v10.y;
        b1.h[2] = (__bf16)v10.z; b1.h[3] = (__bf16)v10.w;
        b1.h[4] = (__bf16)v11.x; b1.h[5] = (__bf16)v11.y;
        b1.h[6] = (__bf16)v11.z; b1.h[7] = (__bf16)v11.w;

        acc0 = __builtin_amdgcn_mfma_f32_16x16x32_bf16(a.s, b0.s,   acc0, 0, 0, 0);
        acc1 = __builtin_amdgcn_mfma_f32_16x16x32_bf16(a.s, b1.s,   acc1, 0, 0, 0);
        acc2 = __builtin_amdgcn_mfma_f32_16x16x32_bf16(a.s, ones.s, acc2, 0, 0, 0);

        lab += 32; e0 += 32; e1 += 32;
    }

    // ---- block reduction: LDS atomics (distinct addresses within a wave) ----
    __shared__ float lsum[16 * 32];
    __shared__ float lcnt[16];
    for (int i = tid; i < 16 * 32; i += THREADS) lsum[i] = 0.f;
    if (tid < 16) lcnt[tid] = 0.f;
    __syncthreads();

#pragma unroll
    for (int r = 0; r < 4; ++r) {
        const int c = (kgrp << 2) + r;          // D row = class
        atomicAdd(&lsum[c * 32 + fcol],      acc0[r]);
        atomicAdd(&lsum[c * 32 + 16 + fcol], acc1[r]);
    }
    if (fcol == 0) {
#pragma unroll
        for (int r = 0; r < 4; ++r) atomicAdd(&lcnt[(kgrp << 2) + r], acc2[r]);
    }
    __syncthreads();

    // FIXED: strided loop — previous version only flushed entries 0..255,
    // silently dropping classes 8..11 sums (passed on random data only because
    // class-means of N(0,1) voxels are ~0.002).
    for (int i = tid; i < C_ * F_; i += THREADS)
        atomicAdd(&g_sums[b * (C_ * F_) + i], lsum[i]);
    if (tid < C_)
        atomicAdd(&g_cnts[b * C_ + tid], lcnt[tid]);
}

__global__ void finalize_kernel(const float* __restrict__ g_sums,
                                const float* __restrict__ g_cnts,
                                const float* __restrict__ proto,
                                float*       __restrict__ out) {
    const int idx = threadIdx.x;               // 0..383 = c*F + f
    if (idx >= C_ * F_) return;
    const int c = idx / F_;
    float p = proto[idx];
#pragma unroll
    for (int b = 0; b < B_; ++b) {
        const float cnt = g_cnts[b * C_ + c];
        const float s   = g_sums[b * C_ * F_ + idx];
        if (cnt > 0.f) p = 0.9f * p + 0.1f * (s / cnt);
    }
    out[idx] = p;
}

extern "C" void kernel_launch(void* const* d_in, const int* in_sizes, int n_in,
                              void* d_out, int out_size, void* d_ws, size_t ws_size,
                              hipStream_t stream) {
    const float* emb    = (const float*)d_in[0];
    const int*   labels = (const int*)d_in[1];
    const float* proto  = (const float*)d_in[2];
    float*       out    = (float*)d_out;

    float* g_sums = (float*)d_ws;              // 768 floats
    float* g_cnts = g_sums + B_ * C_ * F_;     // 24 floats

    hipMemsetAsync(d_ws, 0, (size_t)(B_ * C_ * F_ + B_ * C_) * sizeof(float), stream);

    dim3 grid(NBLK, B_);
    accum_mfma<<<grid, THREADS, 0, stream>>>(emb, labels, g_sums, g_cnts);
    finalize_kernel<<<1, C_ * F_, 0, stream>>>(g_sums, g_cnts, proto, out);
}

// Round 4
// 124.296 us; speedup vs baseline: 5.5927x; 1.1258x over previous
//
#include <hip/hip_runtime.h>

// embeddings [B=2][F=32][N=2359296] f32, labels [B][N] i32, prototypes [12][32] f32
// sums[c][f] = sum_n onehot[c][n] * emb[f][n]  ==  mfma(A=onehot, B=emb)
// mfma_f32_16x16x32_bf16 operand layout: lane l holds outdim = l&15,
// k = 8*(l>>4)+j (j=0..7);  C/D: col = l&15, row = (l>>4)*4 + reg.
#define B_        2
#define F_        32
#define C_        12
#define NVOX      2359296L
#define THREADS   256
#define WAVE_SPAN 576                  // voxels per wave
#define BLOCK_SPAN (WAVE_SPAN * 4)     // 2304
#define NBLK      1024                 // NVOX / BLOCK_SPAN (exact); 2048 total = 8/CU
#define KSTEPS    (WAVE_SPAN / 32)     // 18 mfma K-steps per wave
#define NREP      16                   // replicated global accumulators (atomic relief)

typedef __attribute__((ext_vector_type(8))) short short8;   // 8 bf16 (4 VGPRs)
typedef __attribute__((ext_vector_type(4))) float f32x4;

union ABu { short8 s; __bf16 h[8]; unsigned u[4]; };

__global__ __launch_bounds__(THREADS)
void accum_mfma(const float* __restrict__ emb,
                const int*   __restrict__ labels,
                float*       __restrict__ g_sums,   // [NREP][B][C*F]
                float*       __restrict__ g_cnts) { // [NREP][B][C]
    const int b    = blockIdx.y;
    const int tid  = threadIdx.x;
    const int wv   = tid >> 6;
    const int lane = tid & 63;
    const int fcol = lane & 15;        // feature col (and one-hot class row) index
    const int kgrp = lane >> 4;        // 0..3, k-base = kgrp*8
    const int rep  = blockIdx.x & (NREP - 1);

    const long n0 = (long)blockIdx.x * BLOCK_SPAN + (long)wv * WAVE_SPAN + (kgrp << 3);

    const int*   lab = labels + (long)b * NVOX + n0;
    const float* e0  = emb + (long)(b * F_ + fcol) * NVOX + n0;        // features 0..15
    const float* e1  = e0 + 16L * NVOX;                                // features 16..31

    ABu ones;
#pragma unroll
    for (int p = 0; p < 4; ++p) ones.u[p] = 0x3F803F80u;   // bf16 1.0 pairs

    f32x4 acc0 = {0.f, 0.f, 0.f, 0.f};   // sums, features 0..15
    f32x4 acc1 = {0.f, 0.f, 0.f, 0.f};   // sums, features 16..31
    f32x4 acc2 = {0.f, 0.f, 0.f, 0.f};   // counts (all cols identical)

#pragma unroll 2
    for (int s = 0; s < KSTEPS; ++s) {
        // 8 labels for this lane's k-slots (16-lane groups share -> one transaction)
        int4 L0 = *(const int4*)(lab);
        int4 L1 = *(const int4*)(lab + 4);
        // 8 consecutive voxels of this lane's two features
        float4 v00 = *(const float4*)(e0);
        float4 v01 = *(const float4*)(e0 + 4);
        float4 v10 = *(const float4*)(e1);
        float4 v11 = *(const float4*)(e1 + 4);

        // A fragment: onehot[row=fcol][k] as bf16 {0,1}
        ABu a;
        {
            const int r = fcol;
            unsigned m0 = (min(L0.x, 11) == r) ? 0x3F80u : 0u;
            unsigned m1 = (min(L0.y, 11) == r) ? 0x3F80u : 0u;
            unsigned m2 = (min(L0.z, 11) == r) ? 0x3F80u : 0u;
            unsigned m3 = (min(L0.w, 11) == r) ? 0x3F80u : 0u;
            unsigned m4 = (min(L1.x, 11) == r) ? 0x3F80u : 0u;
            unsigned m5 = (min(L1.y, 11) == r) ? 0x3F80u : 0u;
            unsigned m6 = (min(L1.z, 11) == r) ? 0x3F80u : 0u;
            unsigned m7 = (min(L1.w, 11) == r) ? 0x3F80u : 0u;
            a.u[0] = m0 | (m1 << 16);
            a.u[1] = m2 | (m3 << 16);
            a.u[2] = m4 | (m5 << 16);
            a.u[3] = m6 | (m7 << 16);
        }

        // B fragments: emb cast to bf16 (RNE via v_cvt_pk_bf16_f32)
        ABu b0, b1;
        b0.h[0] = (__bf16)v00.x; b0.h[1] = (__bf16)v00.y;
        b0.h[2] = (__bf16)v00.z; b0.h[3] = (__bf16)v00.w;
        b0.h[4] = (__bf16)v01.x; b0.h[5] = (__bf16)v01.y;
        b0.h[6] = (__bf16)v01.z; b0.h[7] = (__bf16)v01.w;
        b1.h[0] = (__bf16)v10.x; b1.h[1] = (__bf16)v10.y;
        b1.h[2] = (__bf16)v10.z; b1.h[3] = (__bf16)v10.w;
        b1.h[4] = (__bf16)v11.x; b1.h[5] = (__bf16)v11.y;
        b1.h[6] = (__bf16)v11.z; b1.h[7] = (__bf16)v11.w;

        acc0 = __builtin_amdgcn_mfma_f32_16x16x32_bf16(a.s, b0.s,   acc0, 0, 0, 0);
        acc1 = __builtin_amdgcn_mfma_f32_16x16x32_bf16(a.s, b1.s,   acc1, 0, 0, 0);
        acc2 = __builtin_amdgcn_mfma_f32_16x16x32_bf16(a.s, ones.s, acc2, 0, 0, 0);

        lab += 32; e0 += 32; e1 += 32;
    }

    // ---- block reduction: LDS atomics (distinct addresses within a wave) ----
    __shared__ float lsum[16 * 32];
    __shared__ float lcnt[16];
    for (int i = tid; i < 16 * 32; i += THREADS) lsum[i] = 0.f;
    if (tid < 16) lcnt[tid] = 0.f;
    __syncthreads();

#pragma unroll
    for (int r = 0; r < 4; ++r) {
        const int c = (kgrp << 2) + r;          // D row = class
        atomicAdd(&lsum[c * 32 + fcol],      acc0[r]);
        atomicAdd(&lsum[c * 32 + 16 + fcol], acc1[r]);
    }
    if (fcol == 0) {
#pragma unroll
        for (int r = 0; r < 4; ++r) atomicAdd(&lcnt[(kgrp << 2) + r], acc2[r]);
    }
    __syncthreads();

    // flush to replicated global accumulators (rep = blockIdx.x & 15)
    float* gs = g_sums + ((long)rep * B_ + b) * (C_ * F_);
    float* gc = g_cnts + ((long)rep * B_ + b) * C_;
    for (int i = tid; i < C_ * F_; i += THREADS)
        atomicAdd(&gs[i], lsum[i]);
    if (tid < C_)
        atomicAdd(&gc[tid], lcnt[tid]);
}

__global__ void finalize_kernel(const float* __restrict__ g_sums,
                                const float* __restrict__ g_cnts,
                                const float* __restrict__ proto,
                                float*       __restrict__ out) {
    const int idx = threadIdx.x;               // 0..383 = c*F + f
    if (idx >= C_ * F_) return;
    const int c = idx / F_;
    float p = proto[idx];
#pragma unroll
    for (int b = 0; b < B_; ++b) {
        float cnt = 0.f, s = 0.f;
#pragma unroll
        for (int rep = 0; rep < NREP; ++rep) {
            s   += g_sums[((long)rep * B_ + b) * (C_ * F_) + idx];
            cnt += g_cnts[((long)rep * B_ + b) * C_ + c];
        }
        if (cnt > 0.f) p = 0.9f * p + 0.1f * (s / cnt);
    }
    out[idx] = p;
}

extern "C" void kernel_launch(void* const* d_in, const int* in_sizes, int n_in,
                              void* d_out, int out_size, void* d_ws, size_t ws_size,
                              hipStream_t stream) {
    const float* emb    = (const float*)d_in[0];
    const int*   labels = (const int*)d_in[1];
    const float* proto  = (const float*)d_in[2];
    float*       out    = (float*)d_out;

    float* g_sums = (float*)d_ws;                      // NREP*B*C*F floats
    float* g_cnts = g_sums + NREP * B_ * C_ * F_;      // NREP*B*C floats

    hipMemsetAsync(d_ws, 0,
                   (size_t)(NREP * B_ * (C_ * F_ + C_)) * sizeof(float), stream);

    dim3 grid(NBLK, B_);
    accum_mfma<<<grid, THREADS, 0, stream>>>(emb, labels, g_sums, g_cnts);
    finalize_kernel<<<1, C_ * F_, 0, stream>>>(g_sums, g_cnts, proto, out);
}